// Round 13
// baseline (28.031 us; speedup 1.0000x reference)
//
#include <hip/hip_runtime.h>

#define B_SAMPLES 1024
#define T_LEN     2048
#define NLAG      512
#define ROWW      172   // uint words per Z row; 172%32=12 -> balanced quad spread for b128

typedef __fp16   half2_t __attribute__((ext_vector_type(2)));
typedef _Float16 half8_t __attribute__((ext_vector_type(8)));
typedef float    floatx4 __attribute__((ext_vector_type(4)));

__device__ __forceinline__ int slotP(int k) { return k + (k >> 5); }

// One block (256 thr = 4 waves) per sample. Wave w computes G_v for
// v in [8w, 8w+8] via MFMA with q-outer sliding B-windows (D[9] accums).
// Block contribution to the mean is quantized to m * 2^-14 (m integer,
// sum < 2^24) so float atomicAdd into out[0] is EXACT and order-independent
// (deterministic) -- no second kernel, no fence, no counter.
__global__ __launch_bounds__(256) void msd_mfma_kernel(
    const float* __restrict__ alpha, const float* __restrict__ d0p,
    const float* __restrict__ traj, float* __restrict__ out) {
  const int b   = blockIdx.x;
  const int tid = threadIdx.x;
  const int w   = tid >> 6;
  const int l   = tid & 63;
  const int g   = l >> 4;
  const int p16 = l & 15;

  __shared__ __align__(16) unsigned int Zw[16 * ROWW];  // 11008 B
  __shared__ float Pb[2116];                            // padded prefix sums
  __shared__ float Elds[33][16];                        // E(lag): [lag>>4][lag&15]; [32][0]=lag512
  __shared__ float cT[4];                               // per-wave chunk totals
  __shared__ float wred[4];

  // zero pad u in [128,172)
  for (int k = tid; k < 16 * 44; k += 256)
    Zw[(k / 44) * ROWW + 128 + (k % 44)] = 0u;

  // stage: lane owns contiguous t in [512w + 8l, 512w + 8l + 8); float4 loads.
  // sq computed from the f16-ROUNDED values (consistent with the Gram).
  const float4* tr4 = reinterpret_cast<const float4*>(traj) + (size_t)b * (T_LEN / 2);
  float sq[8];
  #pragma unroll
  for (int s = 0; s < 4; ++s) {
    int idx = (w << 8) + (l << 2) + s;      // 256w + 4l + s
    float4 v4 = tr4[idx];
    int t0 = idx << 1;                       // 512w + 8l + 2s
    _Float16 hx0 = (_Float16)v4.x, hy0 = (_Float16)v4.y;
    _Float16 hx1 = (_Float16)v4.z, hy1 = (_Float16)v4.w;
    unsigned int wd0 = (unsigned int)__builtin_bit_cast(unsigned short, hx0)
                     | ((unsigned int)__builtin_bit_cast(unsigned short, hy0) << 16);
    unsigned int wd1 = (unsigned int)__builtin_bit_cast(unsigned short, hx1)
                     | ((unsigned int)__builtin_bit_cast(unsigned short, hy1) << 16);
    Zw[(t0 & 15) * ROWW + (t0 >> 4)] = wd0;
    Zw[((t0 + 1) & 15) * ROWW + ((t0 + 1) >> 4)] = wd1;
    float fx0 = (float)hx0, fy0 = (float)hy0;
    float fx1 = (float)hx1, fy1 = (float)hy1;
    sq[2 * s]     = fmaf(fx0, fx0, fy0 * fy0);
    sq[2 * s + 1] = fmaf(fx1, fx1, fy1 * fy1);
  }

  // wave-local scan of lane sums -> exclusive lane offsets + chunk total
  float ls = ((sq[0] + sq[1]) + (sq[2] + sq[3])) + ((sq[4] + sq[5]) + (sq[6] + sq[7]));
  float run = ls;
  #pragma unroll
  for (int dlt = 1; dlt < 64; dlt <<= 1) {
    float tsh = __shfl_up(run, dlt, 64);
    if (l >= dlt) run += tsh;
  }
  float excl = run - ls;
  if (l == 63) cT[w] = run;                 // wave total (inclusive at lane 63)

  __syncthreads();                          // Zw + cT visible

  // chunk offsets + Ptot from registers; write only the Pb ranges finalize
  // actually reads: P[1..512] (wave 0) and P[1536..2047] (w2 last + wave 3).
  float c0 = cT[0], c1 = cT[1], c2 = cT[2], c3 = cT[3];
  const float Ptot = (c0 + c1) + (c2 + c3);
  float off = 0.f;
  if (w > 0) off += c0;
  if (w > 1) off += c1;
  if (w > 2) off += c2;
  float r2 = off + excl;
  if (w == 0 || w == 3) {
    #pragma unroll
    for (int i = 0; i < 8; ++i) {
      r2 += sq[i];
      Pb[slotP((w << 9) + (l << 3) + i + 1)] = r2;
    }
  } else if (w == 2 && l == 63) {
    float r3 = r2 + ((sq[0] + sq[1]) + (sq[2] + sq[3])) +
               ((sq[4] + sq[5]) + (sq[6] + sq[7]));
    Pb[slotP(1536)] = r3;                   // P[1536] (= wave-2 chunk end)
  }

  const unsigned int* zrow = &Zw[p16 * ROWW];
  const int vS = 8 * w;

  floatx4 D[9];
  #pragma unroll
  for (int r = 0; r < 9; ++r) D[r] = (floatx4){0.f, 0.f, 0.f, 0.f};

  #pragma unroll
  for (int q = 0; q < 8; ++q) {
    const unsigned int* wp = zrow + 16 * q + 4 * g + vS;   // 16B-aligned (vS%4==0)
    uint4 w0 = *reinterpret_cast<const uint4*>(wp);
    uint4 w1 = *reinterpret_cast<const uint4*>(wp + 4);
    uint4 w2 = *reinterpret_cast<const uint4*>(wp + 8);
    unsigned int win[12] = {w0.x, w0.y, w0.z, w0.w,  w1.x, w1.y, w1.z, w1.w,
                            w2.x, w2.y, w2.z, w2.w};
    uint4 aw = *reinterpret_cast<const uint4*>(zrow + 16 * q + 4 * g);
    half8_t aq = __builtin_bit_cast(half8_t, aw);
    #pragma unroll
    for (int r = 0; r < 9; ++r) {
      uint4 bw;
      bw.x = win[r]; bw.y = win[r + 1]; bw.z = win[r + 2]; bw.w = win[r + 3];
      half8_t bf = __builtin_bit_cast(half8_t, bw);
      D[r] = __builtin_amdgcn_mfma_f32_16x16x32_f16(aq, bf, D[r], 0, 0, 0);
    }
  }

  // diagonal extraction: pack (G_2k, G_2k+1) as f16 -> one bpermute per pair.
  // wrap flag depends only on (lane, rr), not on which G.
  float accA[9], accB[9];
  #pragma unroll
  for (int r = 0; r < 9; ++r) { accA[r] = 0.f; accB[r] = 0.f; }

  const int rotb = 4 * g + p16;
  const int idx0 = (l & 48) << 2;

  #pragma unroll
  for (int rr = 0; rr < 4; ++rr) {
    const int src  = idx0 | (((rotb + rr) & 15) << 2);
    const bool wrap = (rotb + rr) >= 16;
    #pragma unroll
    for (int pr = 0; pr < 4; ++pr) {         // G pairs (2pr, 2pr+1)
      half2_t pk = __builtin_amdgcn_cvt_pkrtz(D[2 * pr][rr], D[2 * pr + 1][rr]);
      int got = __builtin_amdgcn_ds_bpermute(src, __builtin_bit_cast(int, pk));
      half2_t gh = __builtin_bit_cast(half2_t, got);
      float lo = (float)gh[0], hi = (float)gh[1];
      accA[2 * pr]     += wrap ? 0.f : lo;
      accB[2 * pr]     += wrap ? lo : 0.f;
      accA[2 * pr + 1] += wrap ? 0.f : hi;
      accB[2 * pr + 1] += wrap ? hi : 0.f;
    }
    {                                        // G_8 single, f32 path
      int got = __builtin_amdgcn_ds_bpermute(src, __builtin_bit_cast(int, D[8][rr]));
      float gv = __builtin_bit_cast(float, got);
      accA[8] += wrap ? 0.f : gv;
      accB[8] += wrap ? gv : 0.f;
    }
  }

  // E(group vS+r-1) = accA[r-1] + accB[r], r=1..8; f16-packed cross-group sum
  #pragma unroll
  for (int k = 0; k < 4; ++k) {
    float e0 = accA[2 * k]     + accB[2 * k + 1];
    float e1 = accA[2 * k + 1] + accB[2 * k + 2];
    half2_t pk = __builtin_amdgcn_cvt_pkrtz(e0, e1);
    half2_t t1 = __builtin_bit_cast(half2_t,
        __shfl_xor(__builtin_bit_cast(int, pk), 16, 64));
    pk = pk + t1;
    half2_t t2 = __builtin_bit_cast(half2_t,
        __shfl_xor(__builtin_bit_cast(int, pk), 32, 64));
    pk = pk + t2;
    if (l < 16) {
      Elds[vS + 2 * k][p16]     = (float)pk[0];
      Elds[vS + 2 * k + 1][p16] = (float)pk[1];
    }
  }
  if (w == 3) {   // lag = 512 = diag_0(G_32): accA[8], f32 reduce
    float E = accA[8];
    E += __shfl_xor(E, 16, 64);
    E += __shfl_xor(E, 32, 64);
    if (l == 0) Elds[32][0] = E;
  }
  __syncthreads();   // Pb + Elds visible to all

  // full-width finalize: 2 lags per thread across 256 threads = lags 1..512
  const float aexp = alpha[b];
  const float c4d0 = 4.f * d0p[b];
  float loc = 0.f;
  #pragma unroll
  for (int c = 0; c < 2; ++c) {
    int lag = c * 256 + tid + 1;
    float E  = Elds[lag >> 4][lag & 15];
    float Pl = Pb[slotP(lag)];
    int mm   = 2048 - lag;
    float Pr = Pb[slotP(mm)];
    float S2  = Pr + (Ptot - Pl);
    float msd = fmaxf((S2 - 2.f * E) / (float)mm, 0.f);
    float theo = c4d0 * __builtin_exp2f(aexp * __builtin_log2f((float)lag));
    float dd = 0.69314718f * (__builtin_log2f(theo + 1e-8f) - __builtin_log2f(msd + 1e-8f));
    loc = fmaf(dd, dd, loc);
  }

  // block reduce 256 threads (fixed order, deterministic)
  #pragma unroll
  for (int dlt = 1; dlt < 64; dlt <<= 1) loc += __shfl_xor(loc, dlt, 64);
  if (l == 0) wred[w] = loc;
  __syncthreads();
  if (tid == 0) {
    float part = (wred[0] + wred[1]) + (wred[2] + wred[3]);
    // contribution to mean = part / 2^19; quantize to m * 2^-14, m integer.
    // All partial sums of out[0] are integers in 2^-14 units, < 2^24 ->
    // float atomicAdd is exact -> order-independent -> deterministic.
    float m = rintf(part * 0.03125f);              // part / 32
    atomicAdd(out, m * 6.103515625e-05f);          // m * 2^-14
  }
}

extern "C" void kernel_launch(void* const* d_in, const int* in_sizes, int n_in,
                              void* d_out, int out_size, void* d_ws, size_t ws_size,
                              hipStream_t stream) {
  const float* alpha = (const float*)d_in[0];
  const float* d0p   = (const float*)d_in[1];
  const float* traj  = (const float*)d_in[2];
  float* out = (float*)d_out;

  hipMemsetAsync(out, 0, 4, stream);   // out[0] = 0.0f each call (graph-capturable)
  msd_mfma_kernel<<<B_SAMPLES, 256, 0, stream>>>(alpha, d0p, traj, out);
}

// Round 14
// 16.172 us; speedup vs baseline: 1.7333x; 1.7333x over previous
//
#include <hip/hip_runtime.h>

#define B_SAMPLES 1024
#define T_LEN     2048
#define NLAG      512
#define ROWW      172   // uint words per Z row; 172%32=12 -> balanced quad spread for b128

typedef __fp16   half2_t __attribute__((ext_vector_type(2)));
typedef _Float16 half8_t __attribute__((ext_vector_type(8)));
typedef float    floatx4 __attribute__((ext_vector_type(4)));

__device__ __forceinline__ int slotP(int k) { return k + (k >> 5); }

// 512 blocks x 512 threads: each block processes TWO samples. Half-block h
// (256 thr = 4 waves) runs the R12 pipeline on sample 2b+h with its own LDS
// set. Halves the workgroup-dispatch count at identical per-CU occupancy
// (2 blocks/CU x 8 waves = 16 waves/CU).
__global__ __launch_bounds__(512, 4) void msd_mfma_kernel(
    const float* __restrict__ alpha, const float* __restrict__ d0p,
    const float* __restrict__ traj, float* __restrict__ partial) {
  const int tid = threadIdx.x;
  const int h   = tid >> 8;        // sample half 0/1
  const int ht  = tid & 255;       // thread id within half
  const int b   = 2 * blockIdx.x + h;
  const int ws  = ht >> 6;         // wave within half (0..3)
  const int l   = tid & 63;
  const int g   = l >> 4;
  const int p16 = l & 15;

  __shared__ __align__(16) unsigned int Zw[2][16 * ROWW];  // 2 x 11008 B
  __shared__ float Pb[2][2116];                            // padded prefix sums
  __shared__ float Elds[2][33][16];                        // E(lag) per half
  __shared__ float cT[2][4];                               // per-wave chunk totals
  __shared__ float wred[2][4];

  // zero pad u in [128,172)
  for (int k = ht; k < 16 * 44; k += 256)
    Zw[h][(k / 44) * ROWW + 128 + (k % 44)] = 0u;

  // stage: lane owns contiguous t in [512ws + 8l, +8); float4 loads.
  // sq computed from the f16-ROUNDED values (consistent with the Gram).
  const float4* tr4 = reinterpret_cast<const float4*>(traj) + (size_t)b * (T_LEN / 2);
  float sq[8];
  #pragma unroll
  for (int s = 0; s < 4; ++s) {
    int idx = (ws << 8) + (l << 2) + s;     // 256ws + 4l + s
    float4 v4 = tr4[idx];
    int t0 = idx << 1;                       // 512ws + 8l + 2s
    _Float16 hx0 = (_Float16)v4.x, hy0 = (_Float16)v4.y;
    _Float16 hx1 = (_Float16)v4.z, hy1 = (_Float16)v4.w;
    unsigned int wd0 = (unsigned int)__builtin_bit_cast(unsigned short, hx0)
                     | ((unsigned int)__builtin_bit_cast(unsigned short, hy0) << 16);
    unsigned int wd1 = (unsigned int)__builtin_bit_cast(unsigned short, hx1)
                     | ((unsigned int)__builtin_bit_cast(unsigned short, hy1) << 16);
    Zw[h][(t0 & 15) * ROWW + (t0 >> 4)] = wd0;
    Zw[h][((t0 + 1) & 15) * ROWW + ((t0 + 1) >> 4)] = wd1;
    float fx0 = (float)hx0, fy0 = (float)hy0;
    float fx1 = (float)hx1, fy1 = (float)hy1;
    sq[2 * s]     = fmaf(fx0, fx0, fy0 * fy0);
    sq[2 * s + 1] = fmaf(fx1, fx1, fy1 * fy1);
  }

  // wave-local scan of lane sums -> exclusive lane offsets + chunk total
  float ls = ((sq[0] + sq[1]) + (sq[2] + sq[3])) + ((sq[4] + sq[5]) + (sq[6] + sq[7]));
  float run = ls;
  #pragma unroll
  for (int dlt = 1; dlt < 64; dlt <<= 1) {
    float tsh = __shfl_up(run, dlt, 64);
    if (l >= dlt) run += tsh;
  }
  float excl = run - ls;
  if (l == 63) cT[h][ws] = run;             // wave total (inclusive at lane 63)

  __syncthreads();                          // Zw + cT visible (both halves)

  // chunk offsets + Ptot from registers; write only the Pb ranges finalize
  // actually reads: P[1..512] (wave 0) and P[1536..2047] (w2 last + wave 3).
  float c0 = cT[h][0], c1 = cT[h][1], c2 = cT[h][2], c3 = cT[h][3];
  const float Ptot = (c0 + c1) + (c2 + c3);
  float off = 0.f;
  if (ws > 0) off += c0;
  if (ws > 1) off += c1;
  if (ws > 2) off += c2;
  float r2 = off + excl;
  if (ws == 0 || ws == 3) {
    #pragma unroll
    for (int i = 0; i < 8; ++i) {
      r2 += sq[i];
      Pb[h][slotP((ws << 9) + (l << 3) + i + 1)] = r2;
    }
  } else if (ws == 2 && l == 63) {
    float r3 = r2 + ((sq[0] + sq[1]) + (sq[2] + sq[3])) +
               ((sq[4] + sq[5]) + (sq[6] + sq[7]));
    Pb[h][slotP(1536)] = r3;                // P[1536] (= wave-2 chunk end)
  }

  const unsigned int* zrow = &Zw[h][p16 * ROWW];
  const int vS = 8 * ws;

  floatx4 D[9];
  #pragma unroll
  for (int r = 0; r < 9; ++r) D[r] = (floatx4){0.f, 0.f, 0.f, 0.f};

  #pragma unroll
  for (int q = 0; q < 8; ++q) {
    const unsigned int* wp = zrow + 16 * q + 4 * g + vS;   // 16B-aligned (vS%4==0)
    uint4 w0 = *reinterpret_cast<const uint4*>(wp);
    uint4 w1 = *reinterpret_cast<const uint4*>(wp + 4);
    uint4 w2 = *reinterpret_cast<const uint4*>(wp + 8);
    unsigned int win[12] = {w0.x, w0.y, w0.z, w0.w,  w1.x, w1.y, w1.z, w1.w,
                            w2.x, w2.y, w2.z, w2.w};
    uint4 aw = *reinterpret_cast<const uint4*>(zrow + 16 * q + 4 * g);
    half8_t aq = __builtin_bit_cast(half8_t, aw);
    #pragma unroll
    for (int r = 0; r < 9; ++r) {
      uint4 bw;
      bw.x = win[r]; bw.y = win[r + 1]; bw.z = win[r + 2]; bw.w = win[r + 3];
      half8_t bf = __builtin_bit_cast(half8_t, bw);
      D[r] = __builtin_amdgcn_mfma_f32_16x16x32_f16(aq, bf, D[r], 0, 0, 0);
    }
  }

  // diagonal extraction: pack (G_2k, G_2k+1) as f16 -> one bpermute per pair.
  // wrap flag depends only on (lane, rr), not on which G.
  float accA[9], accB[9];
  #pragma unroll
  for (int r = 0; r < 9; ++r) { accA[r] = 0.f; accB[r] = 0.f; }

  const int rotb = 4 * g + p16;
  const int idx0 = (l & 48) << 2;

  #pragma unroll
  for (int rr = 0; rr < 4; ++rr) {
    const int src  = idx0 | (((rotb + rr) & 15) << 2);
    const bool wrap = (rotb + rr) >= 16;
    #pragma unroll
    for (int pr = 0; pr < 4; ++pr) {         // G pairs (2pr, 2pr+1)
      half2_t pk = __builtin_amdgcn_cvt_pkrtz(D[2 * pr][rr], D[2 * pr + 1][rr]);
      int got = __builtin_amdgcn_ds_bpermute(src, __builtin_bit_cast(int, pk));
      half2_t gh = __builtin_bit_cast(half2_t, got);
      float lo = (float)gh[0], hi = (float)gh[1];
      accA[2 * pr]     += wrap ? 0.f : lo;
      accB[2 * pr]     += wrap ? lo : 0.f;
      accA[2 * pr + 1] += wrap ? 0.f : hi;
      accB[2 * pr + 1] += wrap ? hi : 0.f;
    }
    {                                        // G_8 single, f32 path
      int got = __builtin_amdgcn_ds_bpermute(src, __builtin_bit_cast(int, D[8][rr]));
      float gv = __builtin_bit_cast(float, got);
      accA[8] += wrap ? 0.f : gv;
      accB[8] += wrap ? gv : 0.f;
    }
  }

  // E(group vS+r-1) = accA[r-1] + accB[r], r=1..8; f16-packed cross-group sum
  #pragma unroll
  for (int k = 0; k < 4; ++k) {
    float e0 = accA[2 * k]     + accB[2 * k + 1];
    float e1 = accA[2 * k + 1] + accB[2 * k + 2];
    half2_t pk = __builtin_amdgcn_cvt_pkrtz(e0, e1);
    half2_t t1 = __builtin_bit_cast(half2_t,
        __shfl_xor(__builtin_bit_cast(int, pk), 16, 64));
    pk = pk + t1;
    half2_t t2 = __builtin_bit_cast(half2_t,
        __shfl_xor(__builtin_bit_cast(int, pk), 32, 64));
    pk = pk + t2;
    if (l < 16) {
      Elds[h][vS + 2 * k][p16]     = (float)pk[0];
      Elds[h][vS + 2 * k + 1][p16] = (float)pk[1];
    }
  }
  if (ws == 3) {   // lag = 512 = diag_0(G_32): accA[8], f32 reduce
    float E = accA[8];
    E += __shfl_xor(E, 16, 64);
    E += __shfl_xor(E, 32, 64);
    if (l == 0) Elds[h][32][0] = E;
  }
  __syncthreads();   // Pb + Elds visible to all

  // full-width finalize: 2 lags per thread across 256 half-threads = lags 1..512
  const float aexp = alpha[b];
  const float c4d0 = 4.f * d0p[b];
  float loc = 0.f;
  #pragma unroll
  for (int c = 0; c < 2; ++c) {
    int lag = c * 256 + ht + 1;
    float E  = Elds[h][lag >> 4][lag & 15];
    float Pl = Pb[h][slotP(lag)];
    int mm   = 2048 - lag;
    float Pr = Pb[h][slotP(mm)];
    float S2  = Pr + (Ptot - Pl);
    float msd = fmaxf((S2 - 2.f * E) / (float)mm, 0.f);
    float theo = c4d0 * __builtin_exp2f(aexp * __builtin_log2f((float)lag));
    float dd = 0.69314718f * (__builtin_log2f(theo + 1e-8f) - __builtin_log2f(msd + 1e-8f));
    loc = fmaf(dd, dd, loc);
  }

  // half-block reduce 256 threads -> partial[b] (fixed order, deterministic)
  #pragma unroll
  for (int dlt = 1; dlt < 64; dlt <<= 1) loc += __shfl_xor(loc, dlt, 64);
  if (l == 0) wred[h][ws] = loc;
  __syncthreads();
  if (ht == 0) partial[b] = (wred[h][0] + wred[h][1]) + (wred[h][2] + wred[h][3]);
}

__global__ __launch_bounds__(256) void reduce_kernel(
    const float* __restrict__ partial, float* __restrict__ out) {
  __shared__ float wsum[4];
  float acc = 0.f;
  for (int i = threadIdx.x; i < B_SAMPLES; i += 256) acc += partial[i];
  for (int off = 32; off > 0; off >>= 1) acc += __shfl_down(acc, off, 64);
  const int wid  = threadIdx.x >> 6;
  const int lane = threadIdx.x & 63;
  if (lane == 0) wsum[wid] = acc;
  __syncthreads();
  if (threadIdx.x == 0) {
    float t = wsum[0] + wsum[1] + wsum[2] + wsum[3];
    out[0] = t * (1.0f / ((float)B_SAMPLES * (float)NLAG));
  }
}

extern "C" void kernel_launch(void* const* d_in, const int* in_sizes, int n_in,
                              void* d_out, int out_size, void* d_ws, size_t ws_size,
                              hipStream_t stream) {
  const float* alpha = (const float*)d_in[0];
  const float* d0p   = (const float*)d_in[1];
  const float* traj  = (const float*)d_in[2];
  float* out     = (float*)d_out;
  float* partial = (float*)d_ws;   // 1024 floats

  msd_mfma_kernel<<<B_SAMPLES / 2, 512, 0, stream>>>(alpha, d0p, traj, partial);
  reduce_kernel<<<1, 256, 0, stream>>>(partial, out);
}

// Round 15
// 15.918 us; speedup vs baseline: 1.7609x; 1.0159x over previous
//
#include <hip/hip_runtime.h>

#define B_SAMPLES 1024
#define T_LEN     2048
#define NLAG      512
#define ROWW      172   // uint words per Z row; 172%32=12 -> balanced quad spread for b128

typedef __fp16   half2_t __attribute__((ext_vector_type(2)));
typedef _Float16 half8_t __attribute__((ext_vector_type(8)));
typedef float    floatx4 __attribute__((ext_vector_type(4)));

__device__ __forceinline__ int slotP(int k) { return k + (k >> 5); }

// One block (512 thr = 8 waves) per sample, VGPR<=64 so all 8 waves/SIMD
// are resident (32 waves/CU). Wave w computes G_v for v in [4w, 4w+4]
// (D[5] accums) via MFMA with q-outer 8-word sliding windows.
__global__ __launch_bounds__(512, 8) void msd_mfma_kernel(
    const float* __restrict__ alpha, const float* __restrict__ d0p,
    const float* __restrict__ traj, float* __restrict__ partial) {
  const int b   = blockIdx.x;
  const int tid = threadIdx.x;
  const int w   = tid >> 6;        // wave 0..7
  const int l   = tid & 63;
  const int g   = l >> 4;
  const int p16 = l & 15;

  __shared__ __align__(16) unsigned int Zw[16 * ROWW];  // 11008 B
  __shared__ float Pb[2116];                            // padded prefix sums
  __shared__ float Elds[33][16];                        // E(lag): [lag>>4][lag&15]
  __shared__ float cT[8];                               // per-wave chunk totals
  __shared__ float wred[8];

  // zero pad u in [128,172)
  for (int k = tid; k < 16 * 44; k += 512)
    Zw[(k / 44) * ROWW + 128 + (k % 44)] = 0u;

  // stage: wave w owns t in [256w, 256w+256); lane owns 4 contiguous t.
  // sq computed from the f16-ROUNDED values (consistent with the Gram).
  const float4* tr4 = reinterpret_cast<const float4*>(traj) + (size_t)b * (T_LEN / 2);
  float sq[4];
  #pragma unroll
  for (int s = 0; s < 2; ++s) {
    int idx = (w << 7) + (l << 1) + s;      // float4 index
    float4 v4 = tr4[idx];
    int t0 = idx << 1;                       // t = 256w + 4l + 2s
    _Float16 hx0 = (_Float16)v4.x, hy0 = (_Float16)v4.y;
    _Float16 hx1 = (_Float16)v4.z, hy1 = (_Float16)v4.w;
    unsigned int wd0 = (unsigned int)__builtin_bit_cast(unsigned short, hx0)
                     | ((unsigned int)__builtin_bit_cast(unsigned short, hy0) << 16);
    unsigned int wd1 = (unsigned int)__builtin_bit_cast(unsigned short, hx1)
                     | ((unsigned int)__builtin_bit_cast(unsigned short, hy1) << 16);
    Zw[(t0 & 15) * ROWW + (t0 >> 4)] = wd0;
    Zw[((t0 + 1) & 15) * ROWW + ((t0 + 1) >> 4)] = wd1;
    float fx0 = (float)hx0, fy0 = (float)hy0;
    float fx1 = (float)hx1, fy1 = (float)hy1;
    sq[2 * s]     = fmaf(fx0, fx0, fy0 * fy0);
    sq[2 * s + 1] = fmaf(fx1, fx1, fy1 * fy1);
  }

  // wave-local scan of lane sums -> exclusive lane offsets + chunk total
  float ls = (sq[0] + sq[1]) + (sq[2] + sq[3]);
  float run = ls;
  #pragma unroll
  for (int dlt = 1; dlt < 64; dlt <<= 1) {
    float tsh = __shfl_up(run, dlt, 64);
    if (l >= dlt) run += tsh;
  }
  float excl = run - ls;
  if (l == 63) cT[w] = run;                 // 256-chunk total

  __syncthreads();                          // Zw + cT visible

  // chunk offsets + Ptot; write only Pb ranges finalize reads:
  // P[1..512] (waves 0,1) and P[1281..2048] (waves 5,6,7).
  float c0 = cT[0], c1 = cT[1], c2 = cT[2], c3 = cT[3];
  float c4 = cT[4], c5 = cT[5], c6 = cT[6], c7 = cT[7];
  const float Ptot = ((c0 + c1) + (c2 + c3)) + ((c4 + c5) + (c6 + c7));
  float off = 0.f;
  if (w > 0) off += c0;
  if (w > 1) off += c1;
  if (w > 2) off += c2;
  if (w > 3) off += c3;
  if (w > 4) off += c4;
  if (w > 5) off += c5;
  if (w > 6) off += c6;
  float r2 = off + excl;
  if (w < 2 || w > 4) {
    #pragma unroll
    for (int i = 0; i < 4; ++i) {
      r2 += sq[i];
      Pb[slotP((w << 8) + (l << 2) + i + 1)] = r2;
    }
  }

  const unsigned int* zrow = &Zw[p16 * ROWW];
  const int vS = 4 * w;

  floatx4 D[5];
  #pragma unroll
  for (int r = 0; r < 5; ++r) D[r] = (floatx4){0.f, 0.f, 0.f, 0.f};

  #pragma unroll
  for (int q = 0; q < 8; ++q) {
    const unsigned int* wp = zrow + 16 * q + 4 * g + vS;   // 16B-aligned (vS%4==0)
    uint4 w0 = *reinterpret_cast<const uint4*>(wp);
    uint4 w1 = *reinterpret_cast<const uint4*>(wp + 4);
    uint4 aw = *reinterpret_cast<const uint4*>(zrow + 16 * q + 4 * g);
    half8_t aq = __builtin_bit_cast(half8_t, aw);
    {
      D[0] = __builtin_amdgcn_mfma_f32_16x16x32_f16(aq, __builtin_bit_cast(half8_t, w0), D[0], 0, 0, 0);
    }
    {
      uint4 bw; bw.x = w0.y; bw.y = w0.z; bw.z = w0.w; bw.w = w1.x;
      D[1] = __builtin_amdgcn_mfma_f32_16x16x32_f16(aq, __builtin_bit_cast(half8_t, bw), D[1], 0, 0, 0);
    }
    {
      uint4 bw; bw.x = w0.z; bw.y = w0.w; bw.z = w1.x; bw.w = w1.y;
      D[2] = __builtin_amdgcn_mfma_f32_16x16x32_f16(aq, __builtin_bit_cast(half8_t, bw), D[2], 0, 0, 0);
    }
    {
      uint4 bw; bw.x = w0.w; bw.y = w1.x; bw.z = w1.y; bw.w = w1.z;
      D[3] = __builtin_amdgcn_mfma_f32_16x16x32_f16(aq, __builtin_bit_cast(half8_t, bw), D[3], 0, 0, 0);
    }
    {
      D[4] = __builtin_amdgcn_mfma_f32_16x16x32_f16(aq, __builtin_bit_cast(half8_t, w1), D[4], 0, 0, 0);
    }
  }

  // diagonal extraction: pack (D0,D1),(D2,D3) as f16 -> one bpermute per pair;
  // D4 takes the f32 path. wrap flag depends only on (lane, rr).
  float accA[5], accB[5];
  #pragma unroll
  for (int r = 0; r < 5; ++r) { accA[r] = 0.f; accB[r] = 0.f; }

  const int rotb = 4 * g + p16;
  const int idx0 = (l & 48) << 2;

  #pragma unroll
  for (int rr = 0; rr < 4; ++rr) {
    const int src  = idx0 | (((rotb + rr) & 15) << 2);
    const bool wrap = (rotb + rr) >= 16;
    #pragma unroll
    for (int pr = 0; pr < 2; ++pr) {         // G pairs (2pr, 2pr+1)
      half2_t pk = __builtin_amdgcn_cvt_pkrtz(D[2 * pr][rr], D[2 * pr + 1][rr]);
      int got = __builtin_amdgcn_ds_bpermute(src, __builtin_bit_cast(int, pk));
      half2_t gh = __builtin_bit_cast(half2_t, got);
      float lo = (float)gh[0], hi = (float)gh[1];
      accA[2 * pr]     += wrap ? 0.f : lo;
      accB[2 * pr]     += wrap ? lo : 0.f;
      accA[2 * pr + 1] += wrap ? 0.f : hi;
      accB[2 * pr + 1] += wrap ? hi : 0.f;
    }
    {                                        // G_4 single, f32 path
      int got = __builtin_amdgcn_ds_bpermute(src, __builtin_bit_cast(int, D[4][rr]));
      float gv = __builtin_bit_cast(float, got);
      accA[4] += wrap ? 0.f : gv;
      accB[4] += wrap ? gv : 0.f;
    }
  }

  // E(group vS+r-1) = accA[r-1] + accB[r], r=1..4; f16-packed cross-group sum
  #pragma unroll
  for (int k = 0; k < 2; ++k) {
    float e0 = accA[2 * k]     + accB[2 * k + 1];
    float e1 = accA[2 * k + 1] + accB[2 * k + 2];
    half2_t pk = __builtin_amdgcn_cvt_pkrtz(e0, e1);
    half2_t t1 = __builtin_bit_cast(half2_t,
        __shfl_xor(__builtin_bit_cast(int, pk), 16, 64));
    pk = pk + t1;
    half2_t t2 = __builtin_bit_cast(half2_t,
        __shfl_xor(__builtin_bit_cast(int, pk), 32, 64));
    pk = pk + t2;
    if (l < 16) {
      Elds[vS + 2 * k][p16]     = (float)pk[0];
      Elds[vS + 2 * k + 1][p16] = (float)pk[1];
    }
  }
  if (w == 7) {   // lag = 512 = diag_0(G_32): accA[4], f32 reduce
    float E = accA[4];
    E += __shfl_xor(E, 16, 64);
    E += __shfl_xor(E, 32, 64);
    if (l == 0) Elds[32][0] = E;
  }
  __syncthreads();   // Pb + Elds visible to all

  // finalize: 1 lag per thread across 512 threads = lags 1..512
  // (lag==512 -> Elds[32][0] naturally via lag>>4, lag&15)
  const float aexp = alpha[b];
  const float c4d0 = 4.f * d0p[b];
  float loc;
  {
    int lag = tid + 1;
    float E  = Elds[lag >> 4][lag & 15];
    float Pl = Pb[slotP(lag)];
    int mm   = 2048 - lag;
    float Pr = Pb[slotP(mm)];
    float S2  = Pr + (Ptot - Pl);
    float msd = fmaxf((S2 - 2.f * E) / (float)mm, 0.f);
    float theo = c4d0 * __builtin_exp2f(aexp * __builtin_log2f((float)lag));
    float dd = 0.69314718f * (__builtin_log2f(theo + 1e-8f) - __builtin_log2f(msd + 1e-8f));
    loc = dd * dd;
  }

  // block reduce 512 threads -> partial[b] (fixed order, deterministic)
  #pragma unroll
  for (int dlt = 1; dlt < 64; dlt <<= 1) loc += __shfl_xor(loc, dlt, 64);
  if (l == 0) wred[w] = loc;
  __syncthreads();
  if (tid == 0) {
    partial[b] = ((wred[0] + wred[1]) + (wred[2] + wred[3])) +
                 ((wred[4] + wred[5]) + (wred[6] + wred[7]));
  }
}

__global__ __launch_bounds__(256) void reduce_kernel(
    const float* __restrict__ partial, float* __restrict__ out) {
  __shared__ float wsum[4];
  float acc = 0.f;
  for (int i = threadIdx.x; i < B_SAMPLES; i += 256) acc += partial[i];
  for (int off = 32; off > 0; off >>= 1) acc += __shfl_down(acc, off, 64);
  const int wid  = threadIdx.x >> 6;
  const int lane = threadIdx.x & 63;
  if (lane == 0) wsum[wid] = acc;
  __syncthreads();
  if (threadIdx.x == 0) {
    float t = wsum[0] + wsum[1] + wsum[2] + wsum[3];
    out[0] = t * (1.0f / ((float)B_SAMPLES * (float)NLAG));
  }
}

extern "C" void kernel_launch(void* const* d_in, const int* in_sizes, int n_in,
                              void* d_out, int out_size, void* d_ws, size_t ws_size,
                              hipStream_t stream) {
  const float* alpha = (const float*)d_in[0];
  const float* d0p   = (const float*)d_in[1];
  const float* traj  = (const float*)d_in[2];
  float* out     = (float*)d_out;
  float* partial = (float*)d_ws;   // 1024 floats

  msd_mfma_kernel<<<B_SAMPLES, 512, 0, stream>>>(alpha, d0p, traj, partial);
  reduce_kernel<<<1, 256, 0, stream>>>(partial, out);
}